// Round 2
// baseline (1409.172 us; speedup 1.0000x reference)
//
#include <hip/hip_runtime.h>

#define NS 32768
#define NLEV 4
#define NF 512
#define HID 512
#define VQD 64
#define CBS 4096

typedef __attribute__((ext_vector_type(8))) short bf16x8;
typedef __attribute__((ext_vector_type(4))) float f32x4;

#define MFMA16(a, b, c) __builtin_amdgcn_mfma_f32_16x16x32_bf16(a, b, c, 0, 0, 0)

__device__ inline unsigned short f2bf(float f) {
    unsigned int u = __float_as_uint(f);
    unsigned int r = (u + 0x7FFFu + ((u >> 16) & 1u)) >> 16;
    return (unsigned short)r;
}
__device__ inline float bf2f(unsigned short s) {
    return __uint_as_float(((unsigned int)s) << 16);
}

// ---- LDS panel [128 rows][128 cols] bf16, XOR-swizzled (G4: 256B stride) ----
// byte = row*256 + col*2, swizzle byte ^= (row&7)<<4 : conflict-free b128 reads.
__device__ __forceinline__ void hp_wr(short* Hp, int row, int col, float v) {
    int byte = (row * 256 + col * 2) ^ ((row & 7) << 4);
    *(short*)((char*)Hp + byte) = (short)f2bf(v);
}
__device__ __forceinline__ bf16x8 hp_rd(const short* Hp, int row, int kbyte) {
    int byte = (row * 256 + kbyte) ^ ((row & 7) << 4);
    return *(const bf16x8*)((const char*)Hp + byte);
}

// ---------------- prep kernels ----------------

__global__ void transpose_all(const float* __restrict__ ew1, const float* __restrict__ ew2,
                              const float* __restrict__ dw1, const float* __restrict__ dw2,
                              unsigned short* __restrict__ ew1t, unsigned short* __restrict__ ew2t,
                              unsigned short* __restrict__ dw1t, unsigned short* __restrict__ dw2t) {
    long i = (long)blockIdx.x * 256 + threadIdx.x;
    const long s1 = (long)NLEV * NF * HID;
    const long s2 = (long)NLEV * HID * VQD;
    const long s3 = (long)NLEV * VQD * HID;
    const long s4 = (long)NLEV * HID * NF;
    const float* src;
    unsigned short* dst;
    int R, C;
    if (i < s1) { src = ew1; dst = ew1t; R = NF; C = HID; }
    else if (i < s1 + s2) { i -= s1; src = ew2; dst = ew2t; R = HID; C = VQD; }
    else if (i < s1 + s2 + s3) { i -= s1 + s2; src = dw1; dst = dw1t; R = VQD; C = HID; }
    else if (i < s1 + s2 + s3 + s4) { i -= s1 + s2 + s3; src = dw2; dst = dw2t; R = HID; C = NF; }
    else return;
    int r = (int)(i % R);
    long t = i / R;
    int c = (int)(t % C);
    int b = (int)(t / C);
    dst[i] = f2bf(src[((long)b * R + r) * C + c]);
}

__global__ void cb_prep(const float* __restrict__ cb, unsigned short* __restrict__ cbb,
                        float* __restrict__ cbn) {
    int i = blockIdx.x * 256 + threadIdx.x;  // l*CBS + n
    if (i >= NLEV * CBS) return;
    const float* row = cb + (long)i * VQD;
    float s = 0.f;
    for (int k = 0; k < VQD; k++) {
        float v = row[k];
        s += v * v;
        cbb[(long)i * VQD + k] = f2bf(v);
    }
    cbn[i] = s;
}

// all levels: x[n][l][f] fp32 -> xb[l][n][f] bf16
__global__ void xconv(const float* __restrict__ x, unsigned short* __restrict__ xb) {
    long i = (long)blockIdx.x * 256 + threadIdx.x;  // one per 8 elements
    int l = (int)(i / ((long)NS * (NF / 8)));
    long rem = i % ((long)NS * (NF / 8));
    int n = (int)(rem >> 6);
    int f8 = ((int)rem & 63) * 8;
    const float* src = x + ((long)n * NLEV + l) * NF + f8;
    float4 f0 = *(const float4*)src;
    float4 f1 = *(const float4*)(src + 4);
    short t[8];
    t[0] = (short)f2bf(f0.x); t[1] = (short)f2bf(f0.y); t[2] = (short)f2bf(f0.z); t[3] = (short)f2bf(f0.w);
    t[4] = (short)f2bf(f1.x); t[5] = (short)f2bf(f1.y); t[6] = (short)f2bf(f1.z); t[7] = (short)f2bf(f1.w);
    *(int4*)(xb + ((long)l * NS + n) * NF + f8) = *(const int4*)t;
}

// ---------------- fused encoder: enc1 + enc2 + VQ argmin + commit ----------------
// 128-row tile, 512 threads (8 waves: wm 2 x wn 4). All operand loads direct
// global->register (w1t/w2t/cbb are L2-resident; xb streamed once). No barriers
// in any K-loop. LDS only for the C-layout -> A-fragment transpose of h
// (panel-by-panel, 32KB, XOR-swizzled) and of z (16KB). 8 barriers total + tail.
__global__ __launch_bounds__(512, 2) void enc_fused(
    const unsigned short* __restrict__ xb, const unsigned short* __restrict__ w1t,
    const float* __restrict__ b1, const unsigned short* __restrict__ w2t,
    const float* __restrict__ b2, const unsigned short* __restrict__ cbb,
    const float* __restrict__ cbn, int* __restrict__ idxo, float* __restrict__ accum) {
    __shared__ __align__(16) short Hp[128 * 128];   // h panel (transpose buffer)
    __shared__ __align__(16) short Zs[2 * 128 * 32];  // z slices
    __shared__ float znp[2][128];
    __shared__ float zn2[128];
    __shared__ float cred;

    const int lvl = blockIdx.y;
    const int m0 = blockIdx.x * 128;
    xb += (long)lvl * NS * NF;
    w1t += (long)lvl * HID * NF;
    b1 += (long)lvl * HID;
    w2t += (long)lvl * VQD * HID;
    b2 += (long)lvl * VQD;
    cbb += (long)lvl * CBS * VQD;
    cbn += (long)lvl * CBS;
    idxo += (long)lvl * NS;

    const int tid = threadIdx.x;
    const int wave = tid >> 6, lane = tid & 63, quad = lane >> 4, lr = lane & 15;
    const int wm = wave >> 2, wn = wave & 3;

    if (tid == 0) cred = 0.f;

    // ---------- P1: h = relu(xb @ w1 + b1), all 4 col-panels in regs ----------
    f32x4 acc[4][4][2];
#pragma unroll
    for (int j = 0; j < 4; j++)
#pragma unroll
        for (int mt = 0; mt < 4; mt++) {
            acc[j][mt][0] = (f32x4){0.f, 0.f, 0.f, 0.f};
            acc[j][mt][1] = (f32x4){0.f, 0.f, 0.f, 0.f};
        }

    const unsigned short* pa = xb + (long)(m0 + wm * 64 + lr) * NF + quad * 8;
    const unsigned short* pb = w1t + (long)(wn * 32 + lr) * NF + quad * 8;
#pragma unroll 2
    for (int s = 0; s < 16; s++) {
        bf16x8 af[4];
#pragma unroll
        for (int mt = 0; mt < 4; mt++)
            af[mt] = *(const bf16x8*)(pa + (long)mt * 16 * NF + s * 32);
#pragma unroll
        for (int j = 0; j < 4; j++) {
            bf16x8 bf0 = *(const bf16x8*)(pb + (long)j * 128 * NF + s * 32);
            bf16x8 bf1 = *(const bf16x8*)(pb + (long)(j * 128 + 16) * NF + s * 32);
#pragma unroll
            for (int mt = 0; mt < 4; mt++) {
                acc[j][mt][0] = MFMA16(af[mt], bf0, acc[j][mt][0]);
                acc[j][mt][1] = MFMA16(af[mt], bf1, acc[j][mt][1]);
            }
        }
    }

    // ---------- P2: z = h @ w2 + b2, h transposed panel-by-panel ----------
    f32x4 az[4];
#pragma unroll
    for (int mt = 0; mt < 4; mt++) az[mt] = (f32x4){0.f, 0.f, 0.f, 0.f};

#pragma unroll
    for (int j = 0; j < 4; j++) {
        if (j) __syncthreads();  // previous panel's reads done
        float bv0 = b1[j * 128 + wn * 32 + lr];
        float bv1 = b1[j * 128 + wn * 32 + 16 + lr];
#pragma unroll
        for (int mt = 0; mt < 4; mt++)
#pragma unroll
            for (int r = 0; r < 4; r++) {
                int row = wm * 64 + mt * 16 + quad * 4 + r;
                float v0 = acc[j][mt][0][r] + bv0; v0 = v0 > 0.f ? v0 : 0.f;
                float v1 = acc[j][mt][1][r] + bv1; v1 = v1 > 0.f ? v1 : 0.f;
                hp_wr(Hp, row, wn * 32 + lr, v0);
                hp_wr(Hp, row, wn * 32 + 16 + lr, v1);
            }
        __syncthreads();
#pragma unroll
        for (int s = 0; s < 4; s++) {
            bf16x8 bz = *(const bf16x8*)&w2t[(long)(wn * 16 + lr) * HID + j * 128 + s * 32 + quad * 8];
#pragma unroll
            for (int mt = 0; mt < 4; mt++) {
                bf16x8 afz = hp_rd(Hp, wm * 64 + mt * 16 + lr, s * 64 + quad * 16);
                az[mt] = MFMA16(afz, bz, az[mt]);
            }
        }
    }

    // ---------- z -> Zs (bf16, [2][128][32]) ----------
    {
        float bz0 = b2[wn * 16 + lr];
        const int col = wn * 16 + lr;
        short* zs = &Zs[(col >> 5) * 4096];
        const int c32 = col & 31;
#pragma unroll
        for (int mt = 0; mt < 4; mt++)
#pragma unroll
            for (int r = 0; r < 4; r++) {
                int row = wm * 64 + mt * 16 + quad * 4 + r;
                zs[row * 32 + c32] = (short)f2bf(az[mt][r] + bz0);
            }
    }
    __syncthreads();

    // ||z||^2 per row
    if (tid < 256) {
        int row = tid >> 1, p = tid & 1;
        const short* zr = &Zs[p * 4096 + row * 32];
        float s2 = 0.f;
#pragma unroll
        for (int j2 = 0; j2 < 32; j2++) {
            float f = bf2f((unsigned short)zr[j2]);
            s2 += f * f;
        }
        znp[p][row] = s2;
    }
    bf16x8 a0 = *(const bf16x8*)&Zs[(wave * 16 + lr) * 32 + quad * 8];
    bf16x8 a1 = *(const bf16x8*)&Zs[4096 + (wave * 16 + lr) * 32 + quad * 8];
    __syncthreads();
    if (tid < 128) zn2[tid] = znp[0][tid] + znp[1][tid];

    // ---------- VQ argmin: codebook direct from L2, no barriers ----------
    float minv[4] = {1e30f, 1e30f, 1e30f, 1e30f};
    int mini[4] = {0, 0, 0, 0};
#pragma unroll 2
    for (int t = 0; t < CBS / 64; t++) {
#pragma unroll
        for (int nt = 0; nt < 4; nt++) {
            const unsigned short* cr = cbb + (long)(t * 64 + nt * 16 + lr) * VQD + quad * 8;
            bf16x8 c0 = *(const bf16x8*)cr;
            bf16x8 c1 = *(const bf16x8*)(cr + 32);
            int n = t * 64 + nt * 16 + lr;
            float cn = cbn[n];
            f32x4 d4 = {0.f, 0.f, 0.f, 0.f};
            d4 = MFMA16(a0, c0, d4);
            d4 = MFMA16(a1, c1, d4);
#pragma unroll
            for (int r = 0; r < 4; r++) {
                float d = fmaf(-2.f, d4[r], cn);
                if (d < minv[r]) { minv[r] = d; mini[r] = n; }
            }
        }
    }

    // ---------- reduce, write idx, commit ----------
    float csum = 0.f;
#pragma unroll
    for (int r = 0; r < 4; r++) {
        float v = minv[r];
        int ix = mini[r];
#pragma unroll
        for (int off = 8; off; off >>= 1) {
            float ov = __shfl_xor(v, off, 64);
            int oi = __shfl_xor(ix, off, 64);
            if (ov < v || (ov == v && oi < ix)) { v = ov; ix = oi; }
        }
        if (lr == 0) {
            int row = wave * 16 + quad * 4 + r;
            idxo[m0 + row] = ix;
            csum += v + zn2[row];
        }
    }
    if (lvl == NLEV - 1) {
        if (lr == 0) atomicAdd(&cred, csum);
        __syncthreads();
        if (tid == 0) atomicAdd(accum + 1, cred);
    }
}

// ---------------- fused decoder: dec1 (gather) + dec2 + MSE ----------------
// Same structure: all operands direct global->register; h2 transposed
// panel-by-panel through the 32KB swizzled LDS panel. acc2[4][8] = 128 VGPR
// holds the full 128x512 output tile; MSE fused at the end.
__global__ __launch_bounds__(512, 2) void dec_fused(
    const unsigned short* __restrict__ cbb, const int* __restrict__ idx,
    const unsigned short* __restrict__ w1t, const float* __restrict__ b1,
    const unsigned short* __restrict__ w2t, const float* __restrict__ b2,
    const unsigned short* __restrict__ xref, float* __restrict__ accum) {
    __shared__ __align__(16) short Hp[128 * 128];
    __shared__ float red[8];

    const int lvl = blockIdx.y;
    const int m0 = blockIdx.x * 128;
    cbb += (long)lvl * CBS * VQD;
    idx += (long)lvl * NS;
    w1t += (long)lvl * HID * VQD;
    b1 += (long)lvl * HID;
    w2t += (long)lvl * NF * HID;
    b2 += (long)lvl * NF;
    xref += (long)lvl * NS * NF;

    const int tid = threadIdx.x;
    const int wave = tid >> 6, lane = tid & 63, quad = lane >> 4, lr = lane & 15;
    const int wm = wave >> 2, wn = wave & 3;

    int iv[4];
#pragma unroll
    for (int mt = 0; mt < 4; mt++) iv[mt] = idx[m0 + wm * 64 + mt * 16 + lr];

    f32x4 acc2[4][8];
#pragma unroll
    for (int mt = 0; mt < 4; mt++)
#pragma unroll
        for (int nt = 0; nt < 8; nt++) acc2[mt][nt] = (f32x4){0.f, 0.f, 0.f, 0.f};

#pragma unroll
    for (int j = 0; j < 4; j++) {
        // ---- dec1 panel j: h2 cols j*128..+127, K=64 ----
        f32x4 ap[4][2];
#pragma unroll
        for (int mt = 0; mt < 4; mt++) {
            ap[mt][0] = (f32x4){0.f, 0.f, 0.f, 0.f};
            ap[mt][1] = (f32x4){0.f, 0.f, 0.f, 0.f};
        }
#pragma unroll
        for (int p = 0; p < 2; p++) {
            bf16x8 bfn[2];
#pragma unroll
            for (int nt = 0; nt < 2; nt++)
                bfn[nt] = *(const bf16x8*)&w1t[(long)(j * 128 + wn * 32 + nt * 16 + lr) * VQD + p * 32 + quad * 8];
#pragma unroll
            for (int mt = 0; mt < 4; mt++) {
                bf16x8 af = *(const bf16x8*)&cbb[(long)iv[mt] * VQD + p * 32 + quad * 8];
                ap[mt][0] = MFMA16(af, bfn[0], ap[mt][0]);
                ap[mt][1] = MFMA16(af, bfn[1], ap[mt][1]);
            }
        }
        if (j) __syncthreads();  // previous panel's reads done
        float bv0 = b1[j * 128 + wn * 32 + lr];
        float bv1 = b1[j * 128 + wn * 32 + 16 + lr];
#pragma unroll
        for (int mt = 0; mt < 4; mt++)
#pragma unroll
            for (int r = 0; r < 4; r++) {
                int row = wm * 64 + mt * 16 + quad * 4 + r;
                float v0 = ap[mt][0][r] + bv0; v0 = v0 > 0.f ? v0 : 0.f;
                float v1 = ap[mt][1][r] + bv1; v1 = v1 > 0.f ? v1 : 0.f;
                hp_wr(Hp, row, wn * 32 + lr, v0);
                hp_wr(Hp, row, wn * 32 + 16 + lr, v1);
            }
        __syncthreads();
        // ---- dec2 partial: K window j*128..+127 ----
#pragma unroll
        for (int s = 0; s < 4; s++) {
            bf16x8 af2[4];
#pragma unroll
            for (int mt = 0; mt < 4; mt++)
                af2[mt] = hp_rd(Hp, wm * 64 + mt * 16 + lr, s * 64 + quad * 16);
#pragma unroll
            for (int nt = 0; nt < 8; nt++) {
                bf16x8 bfr = *(const bf16x8*)&w2t[(long)(wn * 128 + nt * 16 + lr) * HID + j * 128 + s * 32 + quad * 8];
#pragma unroll
                for (int mt = 0; mt < 4; mt++)
                    acc2[mt][nt] = MFMA16(af2[mt], bfr, acc2[mt][nt]);
            }
        }
    }

    // ---- fused MSE epilogue ----
    float lsum = 0.f;
#pragma unroll
    for (int nt = 0; nt < 8; nt++) {
        int col = wn * 128 + nt * 16 + lr;
        float bv = b2[col];
#pragma unroll
        for (int mt = 0; mt < 4; mt++)
#pragma unroll
            for (int r = 0; r < 4; r++) {
                long row = m0 + wm * 64 + mt * 16 + quad * 4 + r;
                float v = acc2[mt][nt][r] + bv - bf2f(xref[row * NF + col]);
                lsum += v * v;
            }
    }
#pragma unroll
    for (int off = 32; off; off >>= 1) lsum += __shfl_down(lsum, off, 64);
    if (lane == 0) red[wave] = lsum;
    __syncthreads();
    if (tid == 0) {
        float s2 = 0.f;
#pragma unroll
        for (int w = 0; w < 8; w++) s2 += red[w];
        atomicAdd(accum, s2);
    }
}

__global__ void finalize_k(const float* __restrict__ accum, float* __restrict__ out) {
    out[0] = accum[0] / ((float)NS * NF * NLEV);
    out[1] = 0.25f * accum[1] / ((float)NS * VQD * NLEV);
}

// ---------------- launch ----------------
extern "C" void kernel_launch(void* const* d_in, const int* in_sizes, int n_in, void* d_out,
                              int out_size, void* d_ws, size_t ws_size, hipStream_t stream) {
    const float* x = (const float*)d_in[0];
    const float* enc_w1 = (const float*)d_in[1];
    const float* enc_b1 = (const float*)d_in[2];
    const float* enc_w2 = (const float*)d_in[3];
    const float* enc_b2 = (const float*)d_in[4];
    const float* dec_w1 = (const float*)d_in[5];
    const float* dec_b1 = (const float*)d_in[6];
    const float* dec_w2 = (const float*)d_in[7];
    const float* dec_b2 = (const float*)d_in[8];
    const float* cb = (const float*)d_in[9];

    char* ws = (char*)d_ws;
    size_t o = 0;
    float* accum = (float*)(ws + o); o += 256;
    unsigned short* enc_w1t = (unsigned short*)(ws + o); o += (size_t)NLEV * HID * NF * 2;
    unsigned short* enc_w2t = (unsigned short*)(ws + o); o += (size_t)NLEV * VQD * HID * 2;
    unsigned short* dec_w1t = (unsigned short*)(ws + o); o += (size_t)NLEV * HID * VQD * 2;
    unsigned short* dec_w2t = (unsigned short*)(ws + o); o += (size_t)NLEV * NF * HID * 2;
    unsigned short* cbb = (unsigned short*)(ws + o); o += (size_t)NLEV * CBS * VQD * 2;
    float* cbn = (float*)(ws + o); o += (size_t)NLEV * CBS * 4;
    unsigned short* xb = (unsigned short*)(ws + o); o += (size_t)NLEV * NS * NF * 2;  // 134 MB
    int* idxp = (int*)(ws + o); o += (size_t)NLEV * NS * 4;

    hipMemsetAsync(accum, 0, 8, stream);

    transpose_all<<<(2 * NLEV * NF * HID + 2 * NLEV * HID * VQD + 255) / 256, 256, 0, stream>>>(
        enc_w1, enc_w2, dec_w1, dec_w2, enc_w1t, enc_w2t, dec_w1t, dec_w2t);
    cb_prep<<<(NLEV * CBS + 255) / 256, 256, 0, stream>>>(cb, cbb, cbn);
    xconv<<<(int)(((long)NLEV * NS * (NF / 8) + 255) / 256), 256, 0, stream>>>(x, xb);

    enc_fused<<<dim3(NS / 128, NLEV), 512, 0, stream>>>(
        xb, enc_w1t, enc_b1, enc_w2t, enc_b2, cbb, cbn, idxp, accum);
    dec_fused<<<dim3(NS / 128, NLEV), 512, 0, stream>>>(
        cbb, idxp, dec_w1t, dec_b1, dec_w2t, dec_b2, xb, accum);

    finalize_k<<<1, 1, 0, stream>>>(accum, (float*)d_out);
}

// Round 3
// 1089.241 us; speedup vs baseline: 1.2937x; 1.2937x over previous
//
#include <hip/hip_runtime.h>

#define NS 32768
#define NLEV 4
#define NF 512
#define HID 512
#define VQD 64
#define CBS 4096

typedef __attribute__((ext_vector_type(8))) short bf16x8;
typedef __attribute__((ext_vector_type(4))) float f32x4;

#define MFMA16(a, b, c) __builtin_amdgcn_mfma_f32_16x16x32_bf16(a, b, c, 0, 0, 0)

__device__ inline unsigned short f2bf(float f) {
    unsigned int u = __float_as_uint(f);
    unsigned int r = (u + 0x7FFFu + ((u >> 16) & 1u)) >> 16;
    return (unsigned short)r;
}
__device__ inline float bf2f(unsigned short s) {
    return __uint_as_float(((unsigned int)s) << 16);
}

// async global->LDS, 16B per lane; lds base must be wave-uniform (HW adds lane*16)
__device__ __forceinline__ void gl16(const void* g, void* l) {
    __builtin_amdgcn_global_load_lds(
        (const __attribute__((address_space(1))) unsigned int*)g,
        (__attribute__((address_space(3))) unsigned int*)l, 16, 0, 0);
}

// ---------------- prep kernels (unchanged from verified 835us base) ----------------

__global__ void transpose_all(const float* __restrict__ ew1, const float* __restrict__ ew2,
                              const float* __restrict__ dw1, const float* __restrict__ dw2,
                              unsigned short* __restrict__ ew1t, unsigned short* __restrict__ ew2t,
                              unsigned short* __restrict__ dw1t, unsigned short* __restrict__ dw2t) {
    long i = (long)blockIdx.x * 256 + threadIdx.x;
    const long s1 = (long)NLEV * NF * HID;
    const long s2 = (long)NLEV * HID * VQD;
    const long s3 = (long)NLEV * VQD * HID;
    const long s4 = (long)NLEV * HID * NF;
    const float* src;
    unsigned short* dst;
    int R, C;
    if (i < s1) { src = ew1; dst = ew1t; R = NF; C = HID; }
    else if (i < s1 + s2) { i -= s1; src = ew2; dst = ew2t; R = HID; C = VQD; }
    else if (i < s1 + s2 + s3) { i -= s1 + s2; src = dw1; dst = dw1t; R = VQD; C = HID; }
    else if (i < s1 + s2 + s3 + s4) { i -= s1 + s2 + s3; src = dw2; dst = dw2t; R = HID; C = NF; }
    else return;
    int r = (int)(i % R);
    long t = i / R;
    int c = (int)(t % C);
    int b = (int)(t / C);
    dst[i] = f2bf(src[((long)b * R + r) * C + c]);
}

__global__ void cb_prep(const float* __restrict__ cb, unsigned short* __restrict__ cbb,
                        float* __restrict__ cbn) {
    int i = blockIdx.x * 256 + threadIdx.x;  // l*CBS + n
    if (i >= NLEV * CBS) return;
    const float* row = cb + (long)i * VQD;
    float s = 0.f;
    for (int k = 0; k < VQD; k++) {
        float v = row[k];
        s += v * v;
        cbb[(long)i * VQD + k] = f2bf(v);
    }
    cbn[i] = s;
}

// all levels: x[n][l][f] fp32 -> xb[l][n][f] bf16
__global__ void xconv(const float* __restrict__ x, unsigned short* __restrict__ xb) {
    long i = (long)blockIdx.x * 256 + threadIdx.x;  // one per 8 elements
    int l = (int)(i / ((long)NS * (NF / 8)));
    long rem = i % ((long)NS * (NF / 8));
    int n = (int)(rem >> 6);
    int f8 = ((int)rem & 63) * 8;
    const float* src = x + ((long)n * NLEV + l) * NF + f8;
    float4 f0 = *(const float4*)src;
    float4 f1 = *(const float4*)(src + 4);
    short t[8];
    t[0] = (short)f2bf(f0.x); t[1] = (short)f2bf(f0.y); t[2] = (short)f2bf(f0.z); t[3] = (short)f2bf(f0.w);
    t[4] = (short)f2bf(f1.x); t[5] = (short)f2bf(f1.y); t[6] = (short)f2bf(f1.z); t[7] = (short)f2bf(f1.w);
    *(int4*)(xb + ((long)l * NS + n) * NF + f8) = *(const int4*)t;
}

// ---------------- 128xBN-tile MFMA GEMM (verified 835us base, used for dec1/dec2) ----
template <int NT, int NTOT, int RELU, int OUT_MODE, int GATHER>
__global__ __launch_bounds__(256) void gemm128(
    const unsigned short* __restrict__ Ab, long astride, long abatch,
    const int* __restrict__ idx,
    const unsigned short* __restrict__ Bt, long bbatch,
    const float* __restrict__ bias, long biasbatch,
    unsigned short* __restrict__ Cb, long cbatch,
    const unsigned short* __restrict__ Xref, long xbatch,
    float* __restrict__ accum, int K) {
    constexpr int BN = NT * 32;
    constexpr int NPAN = NTOT / BN;
    constexpr int BNP = BN + 8;  // padded repack stride
    __shared__ __align__(16) short smem[2 * 128 * 32 + 2 * BN * 32];
    short* As = smem;                   // panel p at p*4096
    short* Bs = smem + 2 * 128 * 32;    // panel p at p*BN*32
    __shared__ float red[4];

    const int bid = blockIdx.x;
    const int inner = bid % (256 * NPAN);
    const int lvl = bid / (256 * NPAN);
    constexpr int CHUNK = 8 * NPAN;
    const int mblk = (inner / CHUNK) * 8 + (inner % CHUNK) / NPAN;
    const int n_blk = inner % NPAN;

    Ab += (long)lvl * abatch;
    Bt += (long)lvl * bbatch;
    bias += (long)lvl * biasbatch;
    if (OUT_MODE == 0) Cb += (long)lvl * cbatch;
    if (OUT_MODE == 2) Xref += (long)lvl * xbatch;
    if (GATHER) idx += (long)lvl * NS;

    const int tid = threadIdx.x;
    const int m0 = mblk * 128;
    const int n0 = n_blk * BN;
    const int wave = tid >> 6, lane = tid & 63, quad = lane >> 4, lr = lane & 15;
    const int wm = wave >> 1, wn = wave & 1;
    const int lrow = lane >> 2;       // 0..15
    const int lcol = (lane & 3) * 8;  // 0,8,16,24

    long idx0 = 0, idx1 = 0;
    if (GATHER) {
        idx0 = idx[m0 + wave * 16 + lrow];
        idx1 = idx[m0 + 64 + wave * 16 + lrow];
    }

    f32x4 acc[4][NT];
#pragma unroll
    for (int i = 0; i < 4; i++)
#pragma unroll
        for (int j = 0; j < NT; j++) acc[i][j] = (f32x4){0.f, 0.f, 0.f, 0.f};

    for (int k0 = 0; k0 < K; k0 += 64) {
#pragma unroll
        for (int p = 0; p < 2; p++) {
            const int kk = k0 + p * 32;
            if (GATHER) {
                gl16(Ab + idx0 * K + kk + lcol, &As[p * 4096 + (wave * 16) * 32]);
                gl16(Ab + idx1 * K + kk + lcol, &As[p * 4096 + (64 + wave * 16) * 32]);
            } else {
                const unsigned short* ga = Ab + (long)(m0 + wave * 16 + lrow) * astride + kk + lcol;
                gl16(ga, &As[p * 4096 + (wave * 16) * 32]);
                gl16(ga + 64 * astride, &As[p * 4096 + (64 + wave * 16) * 32]);
            }
            const unsigned short* gb = Bt + (long)(n0 + wave * 16 + lrow) * K + kk + lcol;
            gl16(gb, &Bs[p * BN * 32 + (wave * 16) * 32]);
            if (NT == 4) gl16(gb + 64 * (long)K, &Bs[p * BN * 32 + (64 + wave * 16) * 32]);
        }
        __syncthreads();
#pragma unroll
        for (int p = 0; p < 2; p++) {
            bf16x8 af[4], bfr[NT];
#pragma unroll
            for (int mt = 0; mt < 4; mt++)
                af[mt] = *(const bf16x8*)&As[p * 4096 + (wm * 64 + mt * 16 + lr) * 32 + quad * 8];
#pragma unroll
            for (int nt = 0; nt < NT; nt++)
                bfr[nt] = *(const bf16x8*)&Bs[p * BN * 32 + (wn * NT * 16 + nt * 16 + lr) * 32 + quad * 8];
#pragma unroll
            for (int mt = 0; mt < 4; mt++)
#pragma unroll
                for (int nt = 0; nt < NT; nt++)
                    acc[mt][nt] = __builtin_amdgcn_mfma_f32_16x16x32_bf16(af[mt], bfr[nt], acc[mt][nt], 0, 0, 0);
        }
        __syncthreads();
    }

    float bvs[NT];
#pragma unroll
    for (int nt = 0; nt < NT; nt++) bvs[nt] = bias[n0 + wn * NT * 16 + nt * 16 + lr];

    if (OUT_MODE == 2) {
        float lsum = 0.f;
#pragma unroll
        for (int nt = 0; nt < NT; nt++) {
            int col = n0 + wn * NT * 16 + nt * 16 + lr;
#pragma unroll
            for (int mt = 0; mt < 4; mt++) {
#pragma unroll
                for (int r = 0; r < 4; r++) {
                    int row = m0 + wm * 64 + mt * 16 + quad * 4 + r;
                    float v = acc[mt][nt][r] + bvs[nt];
                    float d = v - bf2f(Xref[(long)row * NTOT + col]);
                    lsum += d * d;
                }
            }
        }
#pragma unroll
        for (int off = 32; off; off >>= 1) lsum += __shfl_down(lsum, off, 64);
        if (lane == 0) red[wave] = lsum;
        __syncthreads();
        if (tid == 0) atomicAdd(accum, red[0] + red[1] + red[2] + red[3]);
    } else {
        // two-phase LDS repack -> coalesced 16B stores
        short* Ct = smem;  // 64 x BNP overlay
#pragma unroll
        for (int p = 0; p < 2; p++) {
            __syncthreads();
            if (wm == p) {
#pragma unroll
                for (int nt = 0; nt < NT; nt++) {
                    int cl = wn * NT * 16 + nt * 16 + lr;
#pragma unroll
                    for (int mt = 0; mt < 4; mt++) {
#pragma unroll
                        for (int r = 0; r < 4; r++) {
                            int rl = mt * 16 + quad * 4 + r;
                            float v = acc[mt][nt][r] + bvs[nt];
                            if (RELU) v = v > 0.f ? v : 0.f;
                            Ct[rl * BNP + cl] = (short)f2bf(v);
                        }
                    }
                }
            }
            __syncthreads();
            constexpr int PER = (64 * BN / 8) / 256;
#pragma unroll
            for (int j = 0; j < PER; j++) {
                int id = j * 256 + tid;
                int row = id / (BN / 8);
                int seg = id % (BN / 8);
                short tmp[8];
                *(int4*)tmp = *(const int4*)&Ct[row * BNP + seg * 8];
                *(int4*)&Cb[(long)(m0 + p * 64 + row) * NTOT + n0 + seg * 8] = *(const int4*)tmp;
            }
        }
    }
}

// ---------------- fused encoder v3: enc1 + enc2 + VQ argmin + commit ----------------
// 256 threads (4 waves: wm2 x wn2), M-tile 128. m97 regime: gl16 staging,
// single-buffered, 2 barriers/K-step, LDS 50KB -> 3 blocks/CU.
// P1 j-outer over 4 h-panels; az[4][2] accumulates z across panels (h stays on-chip).
// All LDS tiles XOR-swizzled (both-sides: pre-swizzled global src + swizzled read).
__global__ __launch_bounds__(256, 3) void enc_fused(
    const unsigned short* __restrict__ xb, const unsigned short* __restrict__ w1t,
    const float* __restrict__ b1, const unsigned short* __restrict__ w2t,
    const float* __restrict__ b2, const unsigned short* __restrict__ cbb,
    const float* __restrict__ cbn, int* __restrict__ idxo, float* __restrict__ accum) {
    __shared__ __align__(16) char SM[49152];
    __shared__ float znp[2][128];
    __shared__ float zn2[128];
    __shared__ float cred;

    char* AsB = SM;           // 16KB A staging [128][64] swz     (bytes 0..16K)
    char* BsB = SM + 16384;   // 16KB B staging [128][64] swz     (16K..32K)
    char* HpB = SM;           // 32KB h panel [128][128] swz, overlays As+Bs
    char* ZsB = SM + 32768;   // 16KB: W2s [64][128] swz per j; then Zs [128][64] swz
    char* CsB = SM;           // VQ codebook dbuf 2 x 8KB [64][64] swz, overlays As

    const int lvl = blockIdx.y;
    const int m0 = blockIdx.x * 128;
    xb += (long)lvl * NS * NF;
    w1t += (long)lvl * HID * NF;
    b1 += (long)lvl * HID;
    w2t += (long)lvl * VQD * HID;
    b2 += (long)lvl * VQD;
    cbb += (long)lvl * CBS * VQD;
    cbn += (long)lvl * CBS;
    idxo += (long)lvl * NS;

    const int tid = threadIdx.x;
    const int wave = tid >> 6, lane = tid & 63, quad = lane >> 4, lr = lane & 15;
    const int wm = wave >> 1, wn = wave & 1;

    if (tid == 0) cred = 0.f;

    f32x4 az[4][2];
#pragma unroll
    for (int mt = 0; mt < 4; mt++) {
        az[mt][0] = (f32x4){0.f, 0.f, 0.f, 0.f};
        az[mt][1] = (f32x4){0.f, 0.f, 0.f, 0.f};
    }

    for (int j = 0; j < 4; j++) {
        // stage W2 k-window j into ZsB: [64 zcols][128 k] swz (drains at first K-sync)
#pragma unroll
        for (int c = 0; c < 4; c++) {
            int q = c * 256 + tid;
            int row = q >> 4;                      // zcol 0..63 (16 chunks/row)
            int ch = (q & 15) ^ (row & 7);
            gl16(w2t + (long)row * HID + j * 128 + ch * 8, ZsB + c * 4096 + wave * 1024);
        }
        f32x4 acc[4][4];
#pragma unroll
        for (int mt = 0; mt < 4; mt++)
#pragma unroll
            for (int nt = 0; nt < 4; nt++) acc[mt][nt] = (f32x4){0.f, 0.f, 0.f, 0.f};

        for (int step = 0; step < 8; step++) {
            const int k0 = step * 64;
#pragma unroll
            for (int c = 0; c < 4; c++) {  // A: [128 rows][64 k] swz
                int q = c * 256 + tid;
                int row = q >> 3;                  // 8 chunks/row
                int kk = ((q & 7) ^ (row & 7)) * 8;
                gl16(xb + (long)(m0 + row) * NF + k0 + kk, AsB + c * 4096 + wave * 1024);
            }
#pragma unroll
            for (int c = 0; c < 4; c++) {  // B: w1t rows j*128.. [128][64] swz
                int q = c * 256 + tid;
                int row = q >> 3;
                int kk = ((q & 7) ^ (row & 7)) * 8;
                gl16(w1t + (long)(j * 128 + row) * NF + k0 + kk, BsB + c * 4096 + wave * 1024);
            }
            __syncthreads();
#pragma unroll
            for (int p = 0; p < 2; p++) {
                bf16x8 af[4], bf[4];
#pragma unroll
                for (int mt = 0; mt < 4; mt++) {
                    int row = wm * 64 + mt * 16 + lr;
                    af[mt] = *(const bf16x8*)(AsB + row * 128 + ((p * 64 + quad * 16) ^ ((row & 7) << 4)));
                }
#pragma unroll
                for (int nt = 0; nt < 4; nt++) {
                    int row = wn * 64 + nt * 16 + lr;
                    bf[nt] = *(const bf16x8*)(BsB + row * 128 + ((p * 64 + quad * 16) ^ ((row & 7) << 4)));
                }
#pragma unroll
                for (int mt = 0; mt < 4; mt++)
#pragma unroll
                    for (int nt = 0; nt < 4; nt++)
                        acc[mt][nt] = MFMA16(af[mt], bf[nt], acc[mt][nt]);
            }
            __syncthreads();
        }
        // h panel -> Hp (relu+bias), C-layout scatter, swizzled 2B writes
#pragma unroll
        for (int nt = 0; nt < 4; nt++) {
            int col = wn * 64 + nt * 16 + lr;
            float bv = b1[j * 128 + col];
#pragma unroll
            for (int mt = 0; mt < 4; mt++)
#pragma unroll
                for (int r = 0; r < 4; r++) {
                    int row = wm * 64 + mt * 16 + quad * 4 + r;
                    float v = acc[mt][nt][r] + bv;
                    v = v > 0.f ? v : 0.f;
                    *(short*)(HpB + row * 256 + ((col * 2) ^ ((row & 7) << 4))) = (short)f2bf(v);
                }
        }
        __syncthreads();
        // P2 partial: az += h_j @ w2_j (A from Hp, B from W2s)
#pragma unroll
        for (int s = 0; s < 4; s++) {
            bf16x8 ah[4], w2f[2];
#pragma unroll
            for (int mt = 0; mt < 4; mt++) {
                int row = wm * 64 + mt * 16 + lr;
                ah[mt] = *(const bf16x8*)(HpB + row * 256 + ((s * 64 + quad * 16) ^ ((row & 7) << 4)));
            }
#pragma unroll
            for (int nt = 0; nt < 2; nt++) {
                int row = wn * 32 + nt * 16 + lr;
                w2f[nt] = *(const bf16x8*)(ZsB + row * 256 + ((s * 64 + quad * 16) ^ ((row & 7) << 4)));
            }
#pragma unroll
            for (int mt = 0; mt < 4; mt++)
#pragma unroll
                for (int nt = 0; nt < 2; nt++)
                    az[mt][nt] = MFMA16(ah[mt], w2f[nt], az[mt][nt]);
        }
        __syncthreads();
    }

    // ---------- z -> Zs [128 rows][64 dims] swz (bf16) ----------
#pragma unroll
    for (int nt = 0; nt < 2; nt++) {
        int col = wn * 32 + nt * 16 + lr;
        float bz = b2[col];
#pragma unroll
        for (int mt = 0; mt < 4; mt++)
#pragma unroll
            for (int r = 0; r < 4; r++) {
                int row = wm * 64 + mt * 16 + quad * 4 + r;
                float v = az[mt][nt][r] + bz;
                *(short*)(ZsB + row * 128 + ((col * 2) ^ ((row & 7) << 4))) = (short)f2bf(v);
            }
    }
    __syncthreads();

    // stage codebook tile 0 (overlays As; Hp dead) — drains at VQ t=0 sync
#pragma unroll
    for (int c = 0; c < 2; c++) {
        int q = c * 256 + tid;
        int row = q >> 3;
        int kk = ((q & 7) ^ (row & 7)) * 8;
        gl16(cbb + (long)row * VQD + kk, CsB + c * 4096 + wave * 1024);
    }
    // ||z||^2 per row (from bf16 z)
    {
        int row = tid >> 1, p = tid & 1;
        float s2 = 0.f;
#pragma unroll
        for (int c = 0; c < 4; c++) {
            bf16x8 v = *(const bf16x8*)(ZsB + row * 128 + ((p * 64 + c * 16) ^ ((row & 7) << 4)));
#pragma unroll
            for (int e = 0; e < 8; e++) {
                float f = bf2f((unsigned short)v[e]);
                s2 += f * f;
            }
        }
        znp[p][row] = s2;
    }
    // z A-fragments for VQ (each wave: rows wave*16+lr and 64+wave*16+lr)
    bf16x8 a[2][2];
#pragma unroll
    for (int h = 0; h < 2; h++)
#pragma unroll
        for (int p = 0; p < 2; p++) {
            int row = h * 64 + wave * 16 + lr;
            a[h][p] = *(const bf16x8*)(ZsB + row * 128 + ((p * 64 + quad * 16) ^ ((row & 7) << 4)));
        }
    __syncthreads();
    if (tid < 128) zn2[tid] = znp[0][tid] + znp[1][tid];

    // ---------- VQ argmin: maximize s = z.c - 0.5*||c||^2 (C-init trick) ----------
    float maxv[2][4] = {{-1e30f, -1e30f, -1e30f, -1e30f}, {-1e30f, -1e30f, -1e30f, -1e30f}};
    int maxi[2][4] = {{0, 0, 0, 0}, {0, 0, 0, 0}};
#pragma unroll 2
    for (int t = 0; t < CBS / 64; t++) {
        __syncthreads();  // stage(t) drained (issuer vmcnt) + compute(t-1) reads done
        if (t < CBS / 64 - 1) {
#pragma unroll
            for (int c = 0; c < 2; c++) {
                int q = c * 256 + tid;
                int row = q >> 3;
                int kk = ((q & 7) ^ (row & 7)) * 8;
                gl16(cbb + (long)((t + 1) * 64 + row) * VQD + kk,
                     CsB + ((t + 1) & 1) * 8192 + c * 4096 + wave * 1024);
            }
        }
        const char* Cbuf = CsB + (t & 1) * 8192;
#pragma unroll
        for (int nt = 0; nt < 4; nt++) {
            int rowc = nt * 16 + lr;
            int n = t * 64 + rowc;
            float cn = cbn[n];
            bf16x8 c0 = *(const bf16x8*)(Cbuf + rowc * 128 + ((quad * 16) ^ ((rowc & 7) << 4)));
            bf16x8 c1 = *(const bf16x8*)(Cbuf + rowc * 128 + ((64 + quad * 16) ^ ((rowc & 7) << 4)));
            float ci = -0.5f * cn;
#pragma unroll
            for (int h = 0; h < 2; h++) {
                f32x4 d4 = {ci, ci, ci, ci};
                d4 = MFMA16(a[h][0], c0, d4);
                d4 = MFMA16(a[h][1], c1, d4);
#pragma unroll
                for (int r = 0; r < 4; r++) {
                    if (d4[r] > maxv[h][r]) { maxv[h][r] = d4[r]; maxi[h][r] = n; }
                }
            }
        }
    }

    // ---------- reduce across lr, write idx, commit ----------
    float csum = 0.f;
#pragma unroll
    for (int h = 0; h < 2; h++)
#pragma unroll
        for (int r = 0; r < 4; r++) {
            float v = maxv[h][r];
            int ix = maxi[h][r];
#pragma unroll
            for (int off = 8; off; off >>= 1) {
                float ov = __shfl_xor(v, off, 64);
                int oi = __shfl_xor(ix, off, 64);
                if (ov > v || (ov == v && oi < ix)) { v = ov; ix = oi; }
            }
            if (lr == 0) {
                int row = h * 64 + wave * 16 + quad * 4 + r;
                idxo[m0 + row] = ix;
                csum += fmaf(-2.f, v, zn2[row]);  // d_min + ||z||^2
            }
        }
    if (lvl == NLEV - 1) {
        if (lr == 0) atomicAdd(&cred, csum);
        __syncthreads();
        if (tid == 0) atomicAdd(accum + 1, cred);
    }
}

__global__ void finalize_k(const float* __restrict__ accum, float* __restrict__ out) {
    out[0] = accum[0] / ((float)NS * NF * NLEV);
    out[1] = 0.25f * accum[1] / ((float)NS * VQD * NLEV);
}

// ---------------- launch ----------------
extern "C" void kernel_launch(void* const* d_in, const int* in_sizes, int n_in, void* d_out,
                              int out_size, void* d_ws, size_t ws_size, hipStream_t stream) {
    const float* x = (const float*)d_in[0];
    const float* enc_w1 = (const float*)d_in[1];
    const float* enc_b1 = (const float*)d_in[2];
    const float* enc_w2 = (const float*)d_in[3];
    const float* enc_b2 = (const float*)d_in[4];
    const float* dec_w1 = (const float*)d_in[5];
    const float* dec_b1 = (const float*)d_in[6];
    const float* dec_w2 = (const float*)d_in[7];
    const float* dec_b2 = (const float*)d_in[8];
    const float* cb = (const float*)d_in[9];

    char* ws = (char*)d_ws;
    size_t o = 0;
    float* accum = (float*)(ws + o); o += 256;
    unsigned short* enc_w1t = (unsigned short*)(ws + o); o += (size_t)NLEV * HID * NF * 2;
    unsigned short* enc_w2t = (unsigned short*)(ws + o); o += (size_t)NLEV * VQD * HID * 2;
    unsigned short* dec_w1t = (unsigned short*)(ws + o); o += (size_t)NLEV * HID * VQD * 2;
    unsigned short* dec_w2t = (unsigned short*)(ws + o); o += (size_t)NLEV * NF * HID * 2;
    unsigned short* cbb = (unsigned short*)(ws + o); o += (size_t)NLEV * CBS * VQD * 2;
    float* cbn = (float*)(ws + o); o += (size_t)NLEV * CBS * 4;
    unsigned short* xb = (unsigned short*)(ws + o); o += (size_t)NLEV * NS * NF * 2;  // 134 MB
    unsigned short* hb = (unsigned short*)(ws + o); o += (size_t)NLEV * NS * HID * 2; // 134 MB (h2)
    int* idxp = (int*)(ws + o); o += (size_t)NLEV * NS * 4;

    hipMemsetAsync(accum, 0, 8, stream);

    transpose_all<<<(2 * NLEV * NF * HID + 2 * NLEV * HID * VQD + 255) / 256, 256, 0, stream>>>(
        enc_w1, enc_w2, dec_w1, dec_w2, enc_w1t, enc_w2t, dec_w1t, dec_w2t);
    cb_prep<<<(NLEV * CBS + 255) / 256, 256, 0, stream>>>(cb, cbb, cbn);
    xconv<<<(int)(((long)NLEV * NS * (NF / 8) + 255) / 256), 256, 0, stream>>>(x, xb);

    // fused enc1 + enc2 + VQ (replaces enc1 gemm + enc2_vq; h never hits HBM)
    enc_fused<<<dim3(NS / 128, NLEV), 256, 0, stream>>>(
        xb, enc_w1t, enc_b1, enc_w2t, enc_b2, cbb, cbn, idxp, accum);

    const int gBig = 256 * (HID / 128) * NLEV;  // 4096
    // dec1: h2 = relu(cb[idx] @ dec_w1 + b1d) -> hb
    gemm128<4, HID, 1, 0, 1><<<gBig, 256, 0, stream>>>(
        cbb, 0, (long)CBS * VQD, idxp,
        dec_w1t, (long)HID * VQD, dec_b1, HID,
        hb, (long)NS * HID, nullptr, 0, nullptr, VQD);
    // dec2 + fused MSE vs bf16 x
    gemm128<4, NF, 0, 2, 0><<<gBig, 256, 0, stream>>>(
        hb, HID, (long)NS * HID, nullptr,
        dec_w2t, (long)NF * HID, dec_b2, NF,
        nullptr, 0, xb, (long)NS * NF, accum, HID);

    finalize_k<<<1, 1, 0, stream>>>(accum, (float*)d_out);
}